// Round 2
// baseline (154.887 us; speedup 1.0000x reference)
//
#include <hip/hip_runtime.h>
#include <math.h>

using short8 = __attribute__((ext_vector_type(8))) short;   // 8 bf16 in 4 VGPRs
using f32x4  = __attribute__((ext_vector_type(4))) float;
typedef unsigned short ushort_t;

#define MFMA16(a,b,c) __builtin_amdgcn_mfma_f32_16x16x32_bf16((a),(b),(c),0,0,0)

#define BB 2
#define TT 2048
#define CC 512
#define HH 8
#define DD 64
#define N3 1536
#define NCH 32   // chunks of 64 along T

__device__ __forceinline__ float bf2f(ushort_t u){ unsigned int x=((unsigned int)u)<<16; return __builtin_bit_cast(float,x); }
__device__ __forceinline__ ushort_t f2bf(float f){ unsigned int u=__builtin_bit_cast(unsigned int,f); u += 0x7FFFu + ((u>>16)&1u); return (ushort_t)(u>>16); }
__device__ __forceinline__ float elu1(float v){ return v > 0.f ? v + 1.f : expf(v); }

// ---------- prep: bf16 casts, weight transposes, mask diagonal ----------
__global__ void prep(const float* __restrict__ x, const float* __restrict__ amask,
                     const float* __restrict__ W, const float* __restrict__ Pw,
                     ushort_t* __restrict__ xb, ushort_t* __restrict__ wt,
                     ushort_t* __restrict__ pt, float* __restrict__ mdiag)
{
  int gid = blockIdx.x * blockDim.x + threadIdx.x;
  int gsz = gridDim.x * blockDim.x;
  for (int i = gid; i < BB*TT*CC; i += gsz) xb[i] = f2bf(x[i]);
  for (int i = gid; i < CC*N3; i += gsz) { int k = i / N3, n = i - k*N3; wt[n*CC + k] = f2bf(W[i]); }
  for (int i = gid; i < CC*CC; i += gsz) { int k = i >> 9, n = i & 511; pt[n*CC + k] = f2bf(Pw[i]); }
  for (int i = gid; i < BB*TT; i += gsz) { int b = i >> 11, t = i & 2047; mdiag[i] = amask[((size_t)b*TT + t)*TT + t]; }
}

// ---------- GEMM1: qkv = x @ Wqkv + b, fused elu+1 / mask, scatter to heads ----------
__global__ __launch_bounds__(256) void gemm_qkv(const ushort_t* __restrict__ A, const ushort_t* __restrict__ Bt,
    const float* __restrict__ bias, const float* __restrict__ mdiag,
    ushort_t* __restrict__ phiQ, ushort_t* __restrict__ phiK, ushort_t* __restrict__ vB)
{
  __shared__ __align__(16) ushort_t lA[128][40];
  __shared__ __align__(16) ushort_t lB[128][40];
  const int tid = threadIdx.x;
  const int lane = tid & 63, wid = tid >> 6;
  const int g = lane >> 4, lr = lane & 15;
  const int bm = blockIdx.y * 128, bn = blockIdx.x * 128;
  const int wm = (wid >> 1) * 64, wn = (wid & 1) * 64;
  f32x4 acc[4][4] = {};
  for (int k0 = 0; k0 < CC; k0 += 32) {
    #pragma unroll
    for (int it = 0; it < 2; ++it) {
      int flat = tid + it * 256;
      int row = flat >> 2, seg = flat & 3;
      *(short8*)&lA[row][seg*8] = *(const short8*)&A[(size_t)(bm+row)*CC + k0 + seg*8];
      *(short8*)&lB[row][seg*8] = *(const short8*)&Bt[(size_t)(bn+row)*CC + k0 + seg*8];
    }
    __syncthreads();
    short8 af[4], bf[4];
    #pragma unroll
    for (int mf=0;mf<4;++mf) af[mf] = *(const short8*)&lA[wm+mf*16+lr][g*8];
    #pragma unroll
    for (int nf=0;nf<4;++nf) bf[nf] = *(const short8*)&lB[wn+nf*16+lr][g*8];
    #pragma unroll
    for (int mf=0;mf<4;++mf)
      #pragma unroll
      for (int nf=0;nf<4;++nf)
        acc[mf][nf] = MFMA16(af[mf], bf[nf], acc[mf][nf]);
    __syncthreads();
  }
  #pragma unroll
  for (int mf=0;mf<4;++mf) {
    int m0 = bm + wm + mf*16 + g*4;
    #pragma unroll
    for (int nf=0;nf<4;++nf) {
      int n = bn + wn + nf*16 + lr;
      int which = n >> 9, h = (n >> 6) & 7, d = n & 63;
      #pragma unroll
      for (int r=0;r<4;++r) {
        int mm = m0 + r;
        int b = mm >> 11, t = mm & 2047;
        float v = acc[mf][nf][r] + bias[n];
        size_t oidx = (((size_t)(b*HH + h))*TT + t)*DD + d;
        if (which == 0)       phiQ[oidx] = f2bf(elu1(v));
        else if (which == 1)  phiK[oidx] = f2bf(elu1(v) * mdiag[mm]);
        else                  vB[oidx]   = f2bf(v * mdiag[mm]);
      }
    }
  }
}

// ---------- per-chunk state: S_aug^T[j][i] = sum_t V_aug[t][j] * phiK[t][i] ----------
__global__ __launch_bounds__(64) void chunk_state(const ushort_t* __restrict__ phiK,
                                                  const ushort_t* __restrict__ vB,
                                                  float* __restrict__ sChunk)
{
  int bid = blockIdx.x;            // (bh, c)
  int bh = bid >> 5, c = bid & 31;
  int lane = threadIdx.x;
  int g = lane >> 4, lr = lane & 15;
  __shared__ __align__(16) ushort_t KT[64][72];   // KT[i][t]
  __shared__ __align__(16) ushort_t VT[80][72];   // VT[j][t], row 64 = ones
  int t0 = c * 64;
  const ushort_t* kptr = &phiK[((size_t)bh*TT + t0 + lane)*DD];
  const ushort_t* vptr = &vB  [((size_t)bh*TT + t0 + lane)*DD];
  #pragma unroll
  for (int j8 = 0; j8 < 8; ++j8) {
    short8 kk = *(const short8*)&kptr[j8*8];
    short8 vv = *(const short8*)&vptr[j8*8];
    #pragma unroll
    for (int jj=0; jj<8; ++jj) { KT[j8*8+jj][lane] = (ushort_t)kk[jj]; VT[j8*8+jj][lane] = (ushort_t)vv[jj]; }
  }
  VT[64][lane] = 0x3F80;            // bf16(1.0)
  #pragma unroll
  for (int j=65; j<80; ++j) VT[j][lane] = 0;
  __syncthreads();
  float* dst = &sChunk[(size_t)bid * (80*64)];
  #pragma unroll
  for (int mf=0; mf<4; ++mf)
    for (int nf=0; nf<5; ++nf) {
      f32x4 acc = {0.f,0.f,0.f,0.f};
      #pragma unroll
      for (int kf=0; kf<2; ++kf) {
        short8 a = *(const short8*)&KT[mf*16+lr][kf*32 + g*8];
        short8 b = *(const short8*)&VT[nf*16+lr][kf*32 + g*8];
        acc = MFMA16(a, b, acc);
      }
      // C/D: row i = mf*16+4g+r (phiK feature), col j = nf*16+lr (v feature)
      *(f32x4*)&dst[(size_t)(nf*16+lr)*64 + mf*16 + g*4] = acc;
    }
}

// ---------- exclusive prefix over chunks (elementwise) ----------
__global__ void scan_states(const float* __restrict__ sChunk, ushort_t* __restrict__ sPrev)
{
  int bx = blockIdx.x;             // 16*20 blocks
  int bh = bx / 20, seg = bx % 20;
  int e = seg*256 + threadIdx.x;   // 0..5119
  size_t base = (size_t)bh*NCH*5120 + e;
  float run = 0.f;
  for (int c = 0; c < NCH; ++c) {
    sPrev[base + (size_t)c*5120] = f2bf(run);
    run += sChunk[base + (size_t)c*5120];
  }
}

// ---------- per-chunk output: y = (Q@S_prev + tril(QK^T)@V) / den ----------
__global__ __launch_bounds__(64) void chunk_out(const ushort_t* __restrict__ phiQ,
    const ushort_t* __restrict__ phiK, const ushort_t* __restrict__ vB,
    const ushort_t* __restrict__ sPrev, ushort_t* __restrict__ ya)
{
  int bid = blockIdx.x;
  int bh = bid >> 5, c = bid & 31;
  int lane = threadIdx.x, g = lane >> 4, lr = lane & 15;
  __shared__ __align__(16) ushort_t P[64][72];
  __shared__ __align__(16) ushort_t VT[64][72];
  __shared__ float den[64];
  int t0 = c * 64;
  size_t qbase = (size_t)bh*TT + t0;
  // Q fragments (reused for QK^T and Q@S)
  short8 qf[4][2];
  #pragma unroll
  for (int mf=0;mf<4;++mf)
    #pragma unroll
    for (int kf=0;kf<2;++kf)
      qf[mf][kf] = *(const short8*)&phiQ[(qbase + mf*16 + lr)*DD + kf*32 + g*8];
  // QK^T
  f32x4 accs[4][4] = {};
  #pragma unroll
  for (int nf=0;nf<4;++nf)
    #pragma unroll
    for (int kf=0;kf<2;++kf) {
      short8 bk = *(const short8*)&phiK[(qbase + nf*16 + lr)*DD + kf*32 + g*8];
      #pragma unroll
      for (int mf=0;mf<4;++mf) accs[mf][nf] = MFMA16(qf[mf][kf], bk, accs[mf][nf]);
    }
  // Q @ S_prev^T rows (cols 0..63 = numerator, col 64 = denominator-prefix)
  f32x4 accn[4][5] = {};
  size_t sbase = (size_t)bid * 5120;
  #pragma unroll
  for (int nf=0;nf<5;++nf)
    #pragma unroll
    for (int kf=0;kf<2;++kf) {
      short8 bs = *(const short8*)&sPrev[sbase + (size_t)(nf*16+lr)*64 + kf*32 + g*8];
      #pragma unroll
      for (int mf=0;mf<4;++mf) accn[mf][nf] = MFMA16(qf[mf][kf], bs, accn[mf][nf]);
    }
  // stage V^T
  {
    const ushort_t* vptr = &vB[(qbase + lane)*DD];
    #pragma unroll
    for (int j8=0;j8<8;++j8) {
      short8 vv = *(const short8*)&vptr[j8*8];
      #pragma unroll
      for (int jj=0;jj<8;++jj) VT[j8*8+jj][lane] = (ushort_t)vv[jj];
    }
  }
  // masked P -> LDS (bf16)
  #pragma unroll
  for (int mf=0;mf<4;++mf)
    #pragma unroll
    for (int nf=0;nf<4;++nf)
      #pragma unroll
      for (int r=0;r<4;++r) {
        int t = mf*16 + g*4 + r, s = nf*16 + lr;
        P[t][s] = f2bf((s <= t) ? accs[mf][nf][r] : 0.f);
      }
  __syncthreads();
  if (lr == 0)
    #pragma unroll
    for (int mf=0;mf<4;++mf)
      #pragma unroll
      for (int r=0;r<4;++r) den[mf*16 + g*4 + r] = accn[mf][4][r];
  __syncthreads();
  {
    float di = den[lane];
    for (int s=0;s<64;++s) di += bf2f(P[lane][s]);   // masked entries are 0
    di = fmaxf(di, 1e-8f);
    den[lane] = 1.0f / di;
  }
  __syncthreads();
  // P @ V
  short8 pf[4][2];
  #pragma unroll
  for (int mf=0;mf<4;++mf)
    #pragma unroll
    for (int kf=0;kf<2;++kf)
      pf[mf][kf] = *(const short8*)&P[mf*16+lr][kf*32 + g*8];
  #pragma unroll
  for (int nf=0;nf<4;++nf)
    #pragma unroll
    for (int kf=0;kf<2;++kf) {
      short8 vf = *(const short8*)&VT[nf*16+lr][kf*32 + g*8];
      #pragma unroll
      for (int mf=0;mf<4;++mf) accn[mf][nf] = MFMA16(pf[mf][kf], vf, accn[mf][nf]);
    }
  // normalize + write y_attn (bf16, [b*T+t][h*64+d] layout)
  int b = bh >> 3, h = bh & 7;
  #pragma unroll
  for (int mf=0;mf<4;++mf) {
    float inv[4];
    #pragma unroll
    for (int r=0;r<4;++r) inv[r] = den[mf*16 + g*4 + r];
    #pragma unroll
    for (int nf=0;nf<4;++nf)
      #pragma unroll
      for (int r=0;r<4;++r) {
        int t = t0 + mf*16 + g*4 + r;
        int col = h*64 + nf*16 + lr;
        ya[((size_t)b*TT + t)*CC + col] = f2bf(accn[mf][nf][r] * inv[r]);
      }
  }
}

// ---------- GEMM3: out = ya @ c_proj + bias (fp32 out) ----------
__global__ __launch_bounds__(256) void gemm_proj(const ushort_t* __restrict__ A, const ushort_t* __restrict__ Bt,
                                                 const float* __restrict__ bias, float* __restrict__ out)
{
  __shared__ __align__(16) ushort_t lA[128][40];
  __shared__ __align__(16) ushort_t lB[128][40];
  const int tid = threadIdx.x;
  const int lane = tid & 63, wid = tid >> 6;
  const int g = lane >> 4, lr = lane & 15;
  const int bm = blockIdx.y * 128, bn = blockIdx.x * 128;
  const int wm = (wid >> 1) * 64, wn = (wid & 1) * 64;
  f32x4 acc[4][4] = {};
  for (int k0 = 0; k0 < CC; k0 += 32) {
    #pragma unroll
    for (int it = 0; it < 2; ++it) {
      int flat = tid + it * 256;
      int row = flat >> 2, seg = flat & 3;
      *(short8*)&lA[row][seg*8] = *(const short8*)&A[(size_t)(bm+row)*CC + k0 + seg*8];
      *(short8*)&lB[row][seg*8] = *(const short8*)&Bt[(size_t)(bn+row)*CC + k0 + seg*8];
    }
    __syncthreads();
    short8 af[4], bf[4];
    #pragma unroll
    for (int mf=0;mf<4;++mf) af[mf] = *(const short8*)&lA[wm+mf*16+lr][g*8];
    #pragma unroll
    for (int nf=0;nf<4;++nf) bf[nf] = *(const short8*)&lB[wn+nf*16+lr][g*8];
    #pragma unroll
    for (int mf=0;mf<4;++mf)
      #pragma unroll
      for (int nf=0;nf<4;++nf)
        acc[mf][nf] = MFMA16(af[mf], bf[nf], acc[mf][nf]);
    __syncthreads();
  }
  #pragma unroll
  for (int mf=0;mf<4;++mf) {
    int m0 = bm + wm + mf*16 + g*4;
    #pragma unroll
    for (int nf=0;nf<4;++nf) {
      int n = bn + wn + nf*16 + lr;
      #pragma unroll
      for (int r=0;r<4;++r)
        out[(size_t)(m0 + r)*CC + n] = acc[mf][nf][r] + bias[n];
    }
  }
}

extern "C" void kernel_launch(void* const* d_in, const int* in_sizes, int n_in,
                              void* d_out, int out_size, void* d_ws, size_t ws_size,
                              hipStream_t stream)
{
  const float* x     = (const float*)d_in[0];
  const float* amask = (const float*)d_in[1];
  const float* wqkv  = (const float*)d_in[2];
  const float* bqkv  = (const float*)d_in[3];
  const float* wproj = (const float*)d_in[4];
  const float* bproj = (const float*)d_in[5];
  float* out = (float*)d_out;
  char* ws = (char*)d_ws;

  ushort_t* xb    = (ushort_t*)(ws + 0);          // 4096x512 bf16      (4 MB)
  ushort_t* wt    = (ushort_t*)(ws + 4194304);    // 1536x512 bf16      (1.5 MB)
  ushort_t* pt    = (ushort_t*)(ws + 5767168);    // 512x512 bf16       (0.5 MB)
  float*    mdiag = (float*)   (ws + 6291456);    // 4096 f32
  ushort_t* phiQ  = (ushort_t*)(ws + 6307840);    // 16x2048x64 bf16    (4 MB)
  ushort_t* phiK  = (ushort_t*)(ws + 10502144);
  ushort_t* vB    = (ushort_t*)(ws + 14696448);
  ushort_t* ya    = (ushort_t*)(ws + 18890752);   // 4096x512 bf16      (4 MB)
  float*    sChunk= (float*)   (ws + 23085056);   // 512 x 80x64 f32    (10.5 MB)
  ushort_t* sPrev = (ushort_t*)(ws + 33570816);   // 512 x 80x64 bf16   (5.25 MB)

  prep<<<dim3(1024), dim3(256), 0, stream>>>(x, amask, wqkv, wproj, xb, wt, pt, mdiag);
  gemm_qkv<<<dim3(12,32), dim3(256), 0, stream>>>(xb, wt, bqkv, mdiag, phiQ, phiK, vB);
  chunk_state<<<dim3(512), dim3(64), 0, stream>>>(phiK, vB, sChunk);
  scan_states<<<dim3(16*20), dim3(256), 0, stream>>>(sChunk, sPrev);
  chunk_out<<<dim3(512), dim3(64), 0, stream>>>(phiQ, phiK, vB, sPrev, ya);
  gemm_proj<<<dim3(4,32), dim3(256), 0, stream>>>(ya, pt, bproj, out);
}